// Round 3
// baseline (5242.038 us; speedup 1.0000x reference)
//
#include <hip/hip_runtime.h>

#define D 64
#define NEG_INF -9e15f
#define MAXK 16
#define BSH 7                 // bucket = 128 rows
#define BROWS 128
#define MAXNB 1024

// ---------- Phase 0: relation-space precompute ----------
__global__ void relpre_kernel(const float* __restrict__ fc_W, const float* __restrict__ fc_b,
                              const float* __restrict__ rel_emb,
                              float* __restrict__ w1r, float* __restrict__ w2r,
                              float* __restrict__ br) {
    int r = blockIdx.x;
    int j = threadIdx.x;
    const float* rr = rel_emb + r * D;
    float s1 = 0.f, s2 = 0.f;
    for (int d = 0; d < D; ++d) {
        float rv = rr[d];
        s1 += fc_W[j * D + d] * rv;
        s2 += fc_W[(D + j) * D + d] * rv;
    }
    w1r[r * D + j] = s1;
    w2r[r * D + j] = s2;
    if (j == 0) {
        float sb = 0.f;
        for (int d = 0; d < D; ++d) sb += fc_b[d] * rr[d];
        br[r] = sb;
    }
}

// ---------- Phase 1: GAT item embeddings (one wave per item) ----------
__global__ void gat_kernel(const float* __restrict__ item_emb, const float* __restrict__ ent_emb,
                           const int* __restrict__ kg_e, const int* __restrict__ kg_r,
                           const float* __restrict__ w1r, const float* __restrict__ w2r,
                           const float* __restrict__ br,
                           float* __restrict__ x_items, int I, int K, int pad_id) {
    int wave = (blockIdx.x * blockDim.x + threadIdx.x) >> 6;
    int lane = threadIdx.x & 63;
    if (wave >= I) return;
    int i = wave;
    float itemv = item_emb[i * D + lane];
    float entv[MAXK];
    float e[MAXK];
    for (int k = 0; k < K; ++k) {
        int eidx = kg_e[i * K + k];
        int r = kg_r[i * K + k];
        float ev = ent_emb[(long)eidx * D + lane];
        entv[k] = ev;
        float p = itemv * w1r[r * D + lane] + ev * w2r[r * D + lane];
        #pragma unroll
        for (int off = 32; off > 0; off >>= 1) p += __shfl_xor(p, off, 64);
        p += br[r];
        p = p > 0.f ? p : 0.2f * p;
        if (eidx == pad_id) p = NEG_INF;
        e[k] = p;
    }
    float m = e[0];
    for (int k = 1; k < K; ++k) m = fmaxf(m, e[k]);
    float s = 0.f;
    float att[MAXK];
    for (int k = 0; k < K; ++k) { att[k] = expf(e[k] - m); s += att[k]; }
    float inv = 1.f / s;
    float o = itemv;
    for (int k = 0; k < K; ++k) o += att[k] * inv * entv[k];
    x_items[(long)i * D + lane] = o;
}

// ---------- Phase 2a: init x (user part) and acc = x ----------
__global__ void init_kernel(const float* __restrict__ user_emb,
                            float* __restrict__ x, float* __restrict__ acc,
                            int UD, int ND) {
    for (int idx = blockIdx.x * blockDim.x + threadIdx.x; idx < ND;
         idx += gridDim.x * blockDim.x) {
        float v = (idx < UD) ? user_emb[idx] : x[idx];
        x[idx] = v;
        acc[idx] = v;
    }
}

// ---------- Bucket histogram (LDS-staged) ----------
__global__ void bhist_kernel(const int* __restrict__ rows, int* __restrict__ bcnt,
                             int n_edges, int NB) {
    __shared__ int h[MAXNB];
    for (int i = threadIdx.x; i < NB; i += blockDim.x) h[i] = 0;
    __syncthreads();
    for (int e = blockIdx.x * blockDim.x + threadIdx.x; e < n_edges;
         e += gridDim.x * blockDim.x)
        atomicAdd(&h[rows[e] >> BSH], 1);
    __syncthreads();
    for (int i = threadIdx.x; i < NB; i += blockDim.x)
        if (h[i]) atomicAdd(&bcnt[i], h[i]);
}

// ---------- Bucket scan (single block; NB <= 1024) ----------
__global__ void bscan_kernel(const int* __restrict__ bcnt, int* __restrict__ bstart,
                             int* __restrict__ bfill, int NB, int n_edges) {
    __shared__ int tmp[MAXNB];
    int tid = threadIdx.x;
    int v = (tid < NB) ? bcnt[tid] : 0;
    tmp[tid] = v;
    __syncthreads();
    for (int off = 1; off < MAXNB; off <<= 1) {
        int t = (tid >= off) ? tmp[tid - off] : 0;
        __syncthreads();
        tmp[tid] += t;
        __syncthreads();
    }
    if (tid < NB) {
        int ex = tmp[tid] - v;
        bstart[tid] = ex;
        bfill[tid] = ex;
    }
    if (tid == 0) bstart[NB] = n_edges;
}

// ---------- Partition: per-block hist -> segment reserve -> direct write ----------
// edges[pos] = { col | (row&127)<<20 , val_bits }
__global__ void part_kernel(const int* __restrict__ rows, const int* __restrict__ cols,
                            const float* __restrict__ vals,
                            int* __restrict__ bfill, int2* __restrict__ edges,
                            int n_edges, int NB) {
    __shared__ int h[MAXNB];
    __shared__ int base[MAXNB];
    __shared__ int off[MAXNB];
    int nb_blocks = gridDim.x;
    int c0 = (int)((long)n_edges * blockIdx.x / nb_blocks);
    int c1 = (int)((long)n_edges * (blockIdx.x + 1) / nb_blocks);
    for (int i = threadIdx.x; i < NB; i += blockDim.x) { h[i] = 0; off[i] = 0; }
    __syncthreads();
    for (int e = c0 + threadIdx.x; e < c1; e += blockDim.x)
        atomicAdd(&h[rows[e] >> BSH], 1);
    __syncthreads();
    for (int i = threadIdx.x; i < NB; i += blockDim.x)
        if (h[i]) base[i] = atomicAdd(&bfill[i], h[i]);
    __syncthreads();
    for (int e = c0 + threadIdx.x; e < c1; e += blockDim.x) {
        int r = rows[e];
        int b = r >> BSH;
        int pos = base[b] + atomicAdd(&off[b], 1);
        edges[pos] = make_int2(cols[e] | ((r & (BROWS - 1)) << 20), __float_as_int(vals[e]));
    }
}

// ---------- Phase 2b: bucketed SpMV with LDS accumulation ----------
// One block per bucket (128 rows). Edge-parallel: wave per edge, lane = feature.
__global__ __launch_bounds__(256) void
spmv_lds_kernel(const int2* __restrict__ edges, const int* __restrict__ bstart,
                const float* __restrict__ x, float* __restrict__ nxt,
                float* __restrict__ acc, int N) {
    __shared__ float tile[BROWS * D];   // 32 KB
    int b = blockIdx.x;
    for (int i = threadIdx.x; i < BROWS * D; i += 256) tile[i] = 0.f;
    __syncthreads();
    int s = bstart[b];
    int t = bstart[b + 1];
    int lane = threadIdx.x & 63;
    int wv = threadIdx.x >> 6;          // 4 waves
    // wave wv owns quads {s+4wv .. s+4wv+3}, stride 16
    int e = s + wv * 4;
    for (; e + 3 < t; e += 16) {
        int2 p0 = edges[e], p1 = edges[e + 1], p2 = edges[e + 2], p3 = edges[e + 3];
        int c0 = p0.x & 0xFFFFF, c1 = p1.x & 0xFFFFF, c2 = p2.x & 0xFFFFF, c3 = p3.x & 0xFFFFF;
        float g0 = x[(long)c0 * D + lane];
        float g1 = x[(long)c1 * D + lane];
        float g2 = x[(long)c2 * D + lane];
        float g3 = x[(long)c3 * D + lane];
        unsafeAtomicAdd(&tile[((p0.x >> 20) << 6) + lane], __int_as_float(p0.y) * g0);
        unsafeAtomicAdd(&tile[((p1.x >> 20) << 6) + lane], __int_as_float(p1.y) * g1);
        unsafeAtomicAdd(&tile[((p2.x >> 20) << 6) + lane], __int_as_float(p2.y) * g2);
        unsafeAtomicAdd(&tile[((p3.x >> 20) << 6) + lane], __int_as_float(p3.y) * g3);
    }
    // tail: last (partial) quad for this wave
    int qend = e + 4 < t ? e + 4 : t;
    for (; e < qend; ++e) {
        int2 p = edges[e];
        int c = p.x & 0xFFFFF;
        float g = x[(long)c * D + lane];
        unsafeAtomicAdd(&tile[((p.x >> 20) << 6) + lane], __int_as_float(p.y) * g);
    }
    __syncthreads();
    // flush: nxt = tile, acc += tile
    int row0 = b << BSH;
    for (int i = threadIdx.x; i < BROWS * D; i += 256) {
        int row = row0 + (i >> 6);
        if (row >= N) break;
        long o = (long)row0 * D + i;
        float sv = tile[i];
        nxt[o] = sv;
        acc[o] += sv;
    }
}

// ---------- Phase 3: gamma[b] = dot(light[u], light[U+i]) ----------
__global__ void dot_kernel(const float* __restrict__ acc,
                           const int* __restrict__ users, const int* __restrict__ items,
                           float* __restrict__ out, int U, int B) {
    int wave = (blockIdx.x * blockDim.x + threadIdx.x) >> 6;
    int lane = threadIdx.x & 63;
    if (wave >= B) return;
    int u = users[wave];
    int it = items[wave];
    float p = acc[(long)u * D + lane] * acc[(long)(U + it) * D + lane];
    #pragma unroll
    for (int off = 32; off > 0; off >>= 1) p += __shfl_xor(p, off, 64);
    if (lane == 0) out[wave] = p * 0.0625f;
}

extern "C" void kernel_launch(void* const* d_in, const int* in_sizes, int n_in,
                              void* d_out, int out_size, void* d_ws, size_t ws_size,
                              hipStream_t stream) {
    const int*   users    = (const int*)  d_in[0];
    const int*   items    = (const int*)  d_in[1];
    const int*   g_rows   = (const int*)  d_in[2];
    const int*   g_cols   = (const int*)  d_in[3];
    const float* g_vals   = (const float*)d_in[4];
    const float* user_emb = (const float*)d_in[5];
    const float* item_emb = (const float*)d_in[6];
    const float* ent_emb  = (const float*)d_in[7];
    const float* rel_emb  = (const float*)d_in[8];
    const int*   kg_e     = (const int*)  d_in[9];
    const int*   kg_r     = (const int*)  d_in[10];
    const float* fc_W     = (const float*)d_in[11];
    const float* fc_b     = (const float*)d_in[12];
    float* out = (float*)d_out;

    int B       = in_sizes[0];
    int n_edges = in_sizes[2];
    int U       = in_sizes[5] / D;
    int I       = in_sizes[6] / D;
    int NE1     = in_sizes[7] / D;   // E_ENT + 1
    int NR      = in_sizes[8] / D;   // R + 1
    int K       = in_sizes[9] / I;
    int N  = U + I;
    int ND = N * D;
    int NB = (N + BROWS - 1) >> BSH;   // 586 buckets

    // ---- workspace layout ----
    char* basep = (char*)d_ws;
    size_t woff = 0;
    auto alloc = [&](size_t bytes) -> char* {
        char* p = basep + woff;
        woff = (woff + bytes + 255) & ~(size_t)255;
        return p;
    };
    float* x      = (float*)alloc((size_t)ND * 4);
    float* y      = (float*)alloc((size_t)ND * 4);
    float* acc    = (float*)alloc((size_t)ND * 4);
    float* w1r    = (float*)alloc((size_t)NR * D * 4);
    float* w2r    = (float*)alloc((size_t)NR * D * 4);
    float* br     = (float*)alloc((size_t)NR * 4);
    int*   bcnt   = (int*)  alloc((size_t)(NB + 1) * 4);
    int*   bstart = (int*)  alloc((size_t)(NB + 1) * 4);
    int*   bfill  = (int*)  alloc((size_t)(NB + 1) * 4);
    int2*  edges  = (int2*) alloc((size_t)n_edges * 8);

    // Phase 0: relation precompute
    relpre_kernel<<<NR, D, 0, stream>>>(fc_W, fc_b, rel_emb, w1r, w2r, br);

    // Phase 1: GAT item embeddings -> item part of x
    gat_kernel<<<(I + 3) / 4, 256, 0, stream>>>(item_emb, ent_emb, kg_e, kg_r,
                                                w1r, w2r, br,
                                                x + (long)U * D, I, K, NE1 - 1);

    // Bucket partition build
    hipMemsetAsync(bcnt, 0, (size_t)(NB + 1) * 4, stream);
    bhist_kernel<<<512, 256, 0, stream>>>(g_rows, bcnt, n_edges, NB);
    bscan_kernel<<<1, MAXNB, 0, stream>>>(bcnt, bstart, bfill, NB, n_edges);
    part_kernel<<<512, 256, 0, stream>>>(g_rows, g_cols, g_vals, bfill, edges, n_edges, NB);

    // Phase 2a: init
    init_kernel<<<2048, 256, 0, stream>>>(user_emb, x, acc, U * D, ND);

    // Phase 2b: 3 LightGCN layers (bucketed, LDS accumulation)
    float* cur = x;
    float* nxt = y;
    for (int l = 0; l < 3; ++l) {
        spmv_lds_kernel<<<NB, 256, 0, stream>>>(edges, bstart, cur, nxt, acc, N);
        float* t = cur; cur = nxt; nxt = t;
    }

    // Phase 3: batch dot
    dot_kernel<<<(B + 3) / 4, 256, 0, stream>>>(acc, users, items, out, U, B);
}

// Round 4
// 627.485 us; speedup vs baseline: 8.3540x; 8.3540x over previous
//
#include <hip/hip_runtime.h>

#define D 64
#define NEG_INF -9e15f
#define MAXK 16
#define BSH 7                 // bucket = 128 rows
#define BROWS 128
#define MAXNB 1024

// ---------- Phase 0: relation-space precompute ----------
__global__ void relpre_kernel(const float* __restrict__ fc_W, const float* __restrict__ fc_b,
                              const float* __restrict__ rel_emb,
                              float* __restrict__ w1r, float* __restrict__ w2r,
                              float* __restrict__ br) {
    int r = blockIdx.x;
    int j = threadIdx.x;
    const float* rr = rel_emb + r * D;
    float s1 = 0.f, s2 = 0.f;
    for (int d = 0; d < D; ++d) {
        float rv = rr[d];
        s1 += fc_W[j * D + d] * rv;
        s2 += fc_W[(D + j) * D + d] * rv;
    }
    w1r[r * D + j] = s1;
    w2r[r * D + j] = s2;
    if (j == 0) {
        float sb = 0.f;
        for (int d = 0; d < D; ++d) sb += fc_b[d] * rr[d];
        br[r] = sb;
    }
}

// ---------- Phase 1: GAT item embeddings (one wave per item) ----------
__global__ void gat_kernel(const float* __restrict__ item_emb, const float* __restrict__ ent_emb,
                           const int* __restrict__ kg_e, const int* __restrict__ kg_r,
                           const float* __restrict__ w1r, const float* __restrict__ w2r,
                           const float* __restrict__ br,
                           float* __restrict__ x_items, int I, int K, int pad_id) {
    int wave = (blockIdx.x * blockDim.x + threadIdx.x) >> 6;
    int lane = threadIdx.x & 63;
    if (wave >= I) return;
    int i = wave;
    float itemv = item_emb[i * D + lane];
    float entv[MAXK];
    float e[MAXK];
    for (int k = 0; k < K; ++k) {
        int eidx = kg_e[i * K + k];
        int r = kg_r[i * K + k];
        float ev = ent_emb[(long)eidx * D + lane];
        entv[k] = ev;
        float p = itemv * w1r[r * D + lane] + ev * w2r[r * D + lane];
        #pragma unroll
        for (int off = 32; off > 0; off >>= 1) p += __shfl_xor(p, off, 64);
        p += br[r];
        p = p > 0.f ? p : 0.2f * p;
        if (eidx == pad_id) p = NEG_INF;
        e[k] = p;
    }
    float m = e[0];
    for (int k = 1; k < K; ++k) m = fmaxf(m, e[k]);
    float s = 0.f;
    float att[MAXK];
    for (int k = 0; k < K; ++k) { att[k] = expf(e[k] - m); s += att[k]; }
    float inv = 1.f / s;
    float o = itemv;
    for (int k = 0; k < K; ++k) o += att[k] * inv * entv[k];
    x_items[(long)i * D + lane] = o;
}

// ---------- Phase 2a: init x (user part) and acc = x ----------
__global__ void init_kernel(const float* __restrict__ user_emb,
                            float* __restrict__ x, float* __restrict__ acc,
                            int UD, int ND) {
    for (int idx = blockIdx.x * blockDim.x + threadIdx.x; idx < ND;
         idx += gridDim.x * blockDim.x) {
        float v = (idx < UD) ? user_emb[idx] : x[idx];
        x[idx] = v;
        acc[idx] = v;
    }
}

// ---------- Bucket histogram (LDS-staged) ----------
__global__ void bhist_kernel(const int* __restrict__ rows, int* __restrict__ bcnt,
                             int n_edges, int NB) {
    __shared__ int h[MAXNB];
    for (int i = threadIdx.x; i < NB; i += blockDim.x) h[i] = 0;
    __syncthreads();
    for (int e = blockIdx.x * blockDim.x + threadIdx.x; e < n_edges;
         e += gridDim.x * blockDim.x)
        atomicAdd(&h[rows[e] >> BSH], 1);
    __syncthreads();
    for (int i = threadIdx.x; i < NB; i += blockDim.x)
        if (h[i]) atomicAdd(&bcnt[i], h[i]);
}

// ---------- Bucket scan (single block; NB <= 1024) ----------
__global__ void bscan_kernel(const int* __restrict__ bcnt, int* __restrict__ bstart,
                             int* __restrict__ bfill, int NB, int n_edges) {
    __shared__ int tmp[MAXNB];
    int tid = threadIdx.x;
    int v = (tid < NB) ? bcnt[tid] : 0;
    tmp[tid] = v;
    __syncthreads();
    for (int off = 1; off < MAXNB; off <<= 1) {
        int t = (tid >= off) ? tmp[tid - off] : 0;
        __syncthreads();
        tmp[tid] += t;
        __syncthreads();
    }
    if (tid < NB) {
        int ex = tmp[tid] - v;
        bstart[tid] = ex;
        bfill[tid] = ex;
    }
    if (tid == 0) bstart[NB] = n_edges;
}

// ---------- Partition: per-block hist -> segment reserve -> direct write ----------
// etmp[pos] = { col | (row&127)<<20 , val_bits }
__global__ void part_kernel(const int* __restrict__ rows, const int* __restrict__ cols,
                            const float* __restrict__ vals,
                            int* __restrict__ bfill, int2* __restrict__ etmp,
                            int n_edges, int NB) {
    __shared__ int h[MAXNB];
    __shared__ int base[MAXNB];
    __shared__ int off[MAXNB];
    int nb_blocks = gridDim.x;
    int c0 = (int)((long)n_edges * blockIdx.x / nb_blocks);
    int c1 = (int)((long)n_edges * (blockIdx.x + 1) / nb_blocks);
    for (int i = threadIdx.x; i < NB; i += blockDim.x) { h[i] = 0; off[i] = 0; }
    __syncthreads();
    for (int e = c0 + threadIdx.x; e < c1; e += blockDim.x)
        atomicAdd(&h[rows[e] >> BSH], 1);
    __syncthreads();
    for (int i = threadIdx.x; i < NB; i += blockDim.x)
        if (h[i]) base[i] = atomicAdd(&bfill[i], h[i]);
    __syncthreads();
    for (int e = c0 + threadIdx.x; e < c1; e += blockDim.x) {
        int r = rows[e];
        int b = r >> BSH;
        int pos = base[b] + atomicAdd(&off[b], 1);
        etmp[pos] = make_int2(cols[e] | ((r & (BROWS - 1)) << 20), __float_as_int(vals[e]));
    }
}

// ---------- In-bucket counting sort -> exact CSR ----------
// One block per bucket. All scattered writes stay inside the bucket's
// ~54KB segment (L2-resident). Emits row_start/cnt.
__global__ void sort_kernel(const int2* __restrict__ etmp, const int* __restrict__ bstart,
                            int2* __restrict__ edges,
                            int* __restrict__ row_start, int* __restrict__ cnt, int N) {
    __shared__ int h[BROWS];
    __shared__ int excl[BROWS];
    __shared__ int off[BROWS];
    int b = blockIdx.x;
    int s = bstart[b];
    int t = bstart[b + 1];
    int tid = threadIdx.x;
    if (tid < BROWS) { h[tid] = 0; off[tid] = 0; }
    __syncthreads();
    for (int e = s + tid; e < t; e += 256)
        atomicAdd(&h[etmp[e].x >> 20], 1);
    __syncthreads();
    if (tid < BROWS) excl[tid] = h[tid];
    __syncthreads();
    for (int o = 1; o < BROWS; o <<= 1) {
        int v = (tid < BROWS && tid >= o) ? excl[tid - o] : 0;
        __syncthreads();
        if (tid < BROWS) excl[tid] += v;
        __syncthreads();
    }
    int row0 = b << BSH;
    if (tid < BROWS) {
        int ex = excl[tid] - h[tid];       // exclusive
        excl[tid] = ex;
        int row = row0 + tid;
        if (row < N) { row_start[row] = s + ex; cnt[row] = h[tid]; }
    }
    __syncthreads();
    for (int e = s + tid; e < t; e += 256) {
        int2 p = etmp[e];
        int r = p.x >> 20;
        int pos = s + excl[r] + atomicAdd(&off[r], 1);
        edges[pos] = make_int2(p.x & 0xFFFFF, p.y);
    }
}

// ---------- Phase 2b: CSR SpMV, one wave per row, fused acc += ----------
__global__ void spmv_kernel(const int2* __restrict__ edges, const int* __restrict__ row_start,
                            const int* __restrict__ cnt,
                            const float* __restrict__ x, float* __restrict__ nxt,
                            float* __restrict__ acc, int N) {
    long gid = (long)blockIdx.x * blockDim.x + threadIdx.x;
    int row = (int)(gid >> 6);
    int lane = (int)(gid & 63);
    if (row >= N) return;
    int s = row_start[row];
    int n = cnt[row];
    const int2* ep = edges + s;
    float sum = 0.f;
    int e = 0;
    for (; e + 4 <= n; e += 4) {
        int2 p0 = ep[e], p1 = ep[e + 1], p2 = ep[e + 2], p3 = ep[e + 3];
        sum += __int_as_float(p0.y) * x[(long)p0.x * D + lane];
        sum += __int_as_float(p1.y) * x[(long)p1.x * D + lane];
        sum += __int_as_float(p2.y) * x[(long)p2.x * D + lane];
        sum += __int_as_float(p3.y) * x[(long)p3.x * D + lane];
    }
    for (; e < n; ++e) {
        int2 p = ep[e];
        sum += __int_as_float(p.y) * x[(long)p.x * D + lane];
    }
    long o = (long)row * D + lane;
    nxt[o] = sum;
    acc[o] += sum;
}

// ---------- Phase 3: gamma[b] = dot(light[u], light[U+i]) ----------
__global__ void dot_kernel(const float* __restrict__ acc,
                           const int* __restrict__ users, const int* __restrict__ items,
                           float* __restrict__ out, int U, int B) {
    int wave = (blockIdx.x * blockDim.x + threadIdx.x) >> 6;
    int lane = threadIdx.x & 63;
    if (wave >= B) return;
    int u = users[wave];
    int it = items[wave];
    float p = acc[(long)u * D + lane] * acc[(long)(U + it) * D + lane];
    #pragma unroll
    for (int off = 32; off > 0; off >>= 1) p += __shfl_xor(p, off, 64);
    if (lane == 0) out[wave] = p * 0.0625f;
}

extern "C" void kernel_launch(void* const* d_in, const int* in_sizes, int n_in,
                              void* d_out, int out_size, void* d_ws, size_t ws_size,
                              hipStream_t stream) {
    const int*   users    = (const int*)  d_in[0];
    const int*   items    = (const int*)  d_in[1];
    const int*   g_rows   = (const int*)  d_in[2];
    const int*   g_cols   = (const int*)  d_in[3];
    const float* g_vals   = (const float*)d_in[4];
    const float* user_emb = (const float*)d_in[5];
    const float* item_emb = (const float*)d_in[6];
    const float* ent_emb  = (const float*)d_in[7];
    const float* rel_emb  = (const float*)d_in[8];
    const int*   kg_e     = (const int*)  d_in[9];
    const int*   kg_r     = (const int*)  d_in[10];
    const float* fc_W     = (const float*)d_in[11];
    const float* fc_b     = (const float*)d_in[12];
    float* out = (float*)d_out;

    int B       = in_sizes[0];
    int n_edges = in_sizes[2];
    int U       = in_sizes[5] / D;
    int I       = in_sizes[6] / D;
    int NE1     = in_sizes[7] / D;   // E_ENT + 1
    int NR      = in_sizes[8] / D;   // R + 1
    int K       = in_sizes[9] / I;
    int N  = U + I;
    int ND = N * D;
    int NB = (N + BROWS - 1) >> BSH;   // 586 buckets

    // ---- workspace layout ----
    char* basep = (char*)d_ws;
    size_t woff = 0;
    auto alloc = [&](size_t bytes) -> char* {
        char* p = basep + woff;
        woff = (woff + bytes + 255) & ~(size_t)255;
        return p;
    };
    float* x        = (float*)alloc((size_t)ND * 4);
    float* y        = (float*)alloc((size_t)ND * 4);
    float* acc      = (float*)alloc((size_t)ND * 4);
    float* w1r      = (float*)alloc((size_t)NR * D * 4);
    float* w2r      = (float*)alloc((size_t)NR * D * 4);
    float* br       = (float*)alloc((size_t)NR * 4);
    int*   bcnt     = (int*)  alloc((size_t)(NB + 1) * 4);
    int*   bstart   = (int*)  alloc((size_t)(NB + 1) * 4);
    int*   bfill    = (int*)  alloc((size_t)(NB + 1) * 4);
    int*   row_start= (int*)  alloc((size_t)N * 4);
    int*   cnt      = (int*)  alloc((size_t)N * 4);
    int2*  edges    = (int2*) alloc((size_t)n_edges * 8);
    // partition temp aliases x+y (38.4MB >= 32MB); CSR build completes
    // before gat/init write x/y.
    int2*  etmp     = (int2*)x;

    // ---- CSR build (runs first; etmp occupies x/y region) ----
    hipMemsetAsync(bcnt, 0, (size_t)(NB + 1) * 4, stream);
    bhist_kernel<<<512, 256, 0, stream>>>(g_rows, bcnt, n_edges, NB);
    bscan_kernel<<<1, MAXNB, 0, stream>>>(bcnt, bstart, bfill, NB, n_edges);
    part_kernel<<<512, 256, 0, stream>>>(g_rows, g_cols, g_vals, bfill, etmp, n_edges, NB);
    sort_kernel<<<NB, 256, 0, stream>>>(etmp, bstart, edges, row_start, cnt, N);

    // Phase 0: relation precompute
    relpre_kernel<<<NR, D, 0, stream>>>(fc_W, fc_b, rel_emb, w1r, w2r, br);

    // Phase 1: GAT item embeddings -> item part of x
    gat_kernel<<<(I + 3) / 4, 256, 0, stream>>>(item_emb, ent_emb, kg_e, kg_r,
                                                w1r, w2r, br,
                                                x + (long)U * D, I, K, NE1 - 1);

    // Phase 2a: init
    init_kernel<<<2048, 256, 0, stream>>>(user_emb, x, acc, U * D, ND);

    // Phase 2b: 3 LightGCN layers (exact CSR, wave per row)
    float* cur = x;
    float* nxt = y;
    for (int l = 0; l < 3; ++l) {
        long total = (long)N * 64;
        int blocks = (int)((total + 255) / 256);
        spmv_kernel<<<blocks, 256, 0, stream>>>(edges, row_start, cnt, cur, nxt, acc, N);
        float* t = cur; cur = nxt; nxt = t;
    }

    // Phase 3: batch dot
    dot_kernel<<<(B + 3) / 4, 256, 0, stream>>>(acc, users, items, out, U, B);
}